// Round 10
// baseline (61.455 us; speedup 1.0000x reference)
//
#include <hip/hip_runtime.h>
#include <hip/hip_bf16.h>
#include <math.h>

#define B_ROWS 16384
#define DIM 1024

typedef __attribute__((ext_vector_type(8))) short s16x8;
typedef __attribute__((ext_vector_type(4))) float f32x4;

static __device__ __forceinline__ unsigned short f2bf(float f) {
    union { float f; unsigned u; } v; v.f = f;
    unsigned r = v.u + 0x7FFF + ((v.u >> 16) & 1);  // RNE
    return (unsigned short)(r >> 16);
}

// async global -> LDS, 16 bytes per lane; lds base wave-uniform, HW adds lane*16
static __device__ __forceinline__ void gload16(const unsigned short* g, unsigned short* l) {
    __builtin_amdgcn_global_load_lds(
        (const __attribute__((address_space(1))) unsigned int*)g,
        (__attribute__((address_space(3))) unsigned int*)l, 16, 0, 0);
}

// ---------------------------------------------------------------------------
// prep (4274 blocks):
//  [0,4096):  x f32 -> xb bf16 streaming convert (coalesced float4/short4)
//  [4096,4272): weight transpose+convert+pad via 64x64 LDS tiles
//  4272: cross-net P-vector rows into W1b spare rows (GEMM columns)
//  4273: cross-net scalar constants czz[6]
// Cross-net closed form (exact algebra):
//   z_i = s^3(x.P3_i)+s^2(x.P2_i)+s(x.P1_i)+(x.Wl)+s^2 C2_i+s C1_i+C0_i
// W1b rows: 500:P3_0 501:P2_0 502:P1_0 503:P3_1 504:P2_1 505:P1_1 506:Wl
//           507:ones (row-sum s)  508-511: zero
// ---------------------------------------------------------------------------
__global__ __launch_bounds__(256) void prep(
    const float* __restrict__ x, unsigned short* __restrict__ xb,
    const float* __restrict__ W1, const float* __restrict__ W2,
    const float* __restrict__ W3,
    const float* __restrict__ cw, const float* __restrict__ cb,
    const float* __restrict__ Wl,
    unsigned short* __restrict__ W1b, unsigned short* __restrict__ W2b,
    unsigned short* __restrict__ W3b,
    float* __restrict__ czz) {
    __shared__ unsigned short tile[64][72];
    __shared__ float red[4][6];
    const int tid = threadIdx.x;
    const int blk = blockIdx.x;

    if (blk < 4096) {
        // ---- x convert: 4096 f32 per block ----
        const float* src = x + (size_t)blk * 4096;
        unsigned short* dst = xb + (size_t)blk * 4096;
#pragma unroll
        for (int r = 0; r < 4; ++r) {
            float4 f = *(const float4*)(src + r * 1024 + tid * 4);
            short4 h;
            h.x = (short)f2bf(f.x); h.y = (short)f2bf(f.y);
            h.z = (short)f2bf(f.z); h.w = (short)f2bf(f.w);
            *(short4*)(dst + r * 1024 + tid * 4) = h;
        }
    } else if (blk < 4272) {
        // ---- weight transpose tile ----
        const int w = blk - 4096;
        const float* src; unsigned short* dst;
        int kt, nt, Ksrc, Nsrc, ldDst;
        bool skipHi = false;
        if (w < 128)      { kt = w & 15;         nt = w >> 4;         src = W1; dst = W1b; Ksrc = 1024; Nsrc = 500; ldDst = 1024; skipHi = true; }
        else if (w < 160) { kt = (w - 128) & 7;  nt = (w - 128) >> 3; src = W2; dst = W2b; Ksrc = 500;  Nsrc = 200; ldDst = 512;  }
        else              { kt = (w - 160) & 3;  nt = (w - 160) >> 2; src = W3; dst = W3b; Ksrc = 200;  Nsrc = 200; ldDst = 256;  }
        const int k0 = kt << 6, n0 = nt << 6;
        {
            const int r = tid >> 2, c0 = (tid & 3) << 4;
            const int kk = k0 + r;
#pragma unroll
            for (int i = 0; i < 16; ++i) {
                const int nn = n0 + c0 + i;
                const float v = (kk < Ksrc && nn < Nsrc) ? src[(size_t)kk * Nsrc + nn] : 0.f;
                tile[r][c0 + i] = f2bf(v);
            }
        }
        __syncthreads();
        {
            const int n = tid >> 2, kc = (tid & 3) << 4;
            if (!(skipHi && (n0 + n) >= 500)) {   // rows 500-511 owned by blk 4272
                unsigned short* o = dst + (size_t)(n0 + n) * ldDst + k0 + kc;
#pragma unroll
                for (int i = 0; i < 16; ++i) o[i] = tile[kc + i][n];
            }
        }
    } else if (blk == 4272) {
        // ---- P-vector rows ----
#pragma unroll
        for (int q = 0; q < 4; ++q) {
            const int k = tid * 4 + q;
            const float wl = Wl[k];
            const float a1 = cw[k],         a2 = cw[1024 + k],  a3 = cw[2048 + k];
            const float d1_ = cw[3072 + k], d2_ = cw[4096 + k], d3_ = cw[5120 + k];
            W1b[(size_t)500 * 1024 + k] = f2bf(a1 * a2 * a3 * wl);
            W1b[(size_t)501 * 1024 + k] = f2bf(a2 * a3 * wl);
            W1b[(size_t)502 * 1024 + k] = f2bf(a3 * wl);
            W1b[(size_t)503 * 1024 + k] = f2bf(d1_ * d2_ * d3_ * wl);
            W1b[(size_t)504 * 1024 + k] = f2bf(d2_ * d3_ * wl);
            W1b[(size_t)505 * 1024 + k] = f2bf(d3_ * wl);
            W1b[(size_t)506 * 1024 + k] = f2bf(wl);
            W1b[(size_t)507 * 1024 + k] = 0x3F80;   // bf16 1.0
            W1b[(size_t)508 * 1024 + k] = 0;
            W1b[(size_t)509 * 1024 + k] = 0;
            W1b[(size_t)510 * 1024 + k] = 0;
            W1b[(size_t)511 * 1024 + k] = 0;
        }
    } else {
        // ---- C scalars (f32 exact) ----
        float c[6] = {0.f, 0.f, 0.f, 0.f, 0.f, 0.f};
#pragma unroll
        for (int q = 0; q < 4; ++q) {
            const int k = tid * 4 + q;
            const float wl = Wl[k];
            {
                const float w2 = cw[1024 + k], w3 = cw[2048 + k];
                const float b1 = cb[k], b2 = cb[1024 + k], b3 = cb[2048 + k];
                c[0] += w2 * w3 * b1 * wl;
                c[1] += w3 * b2 * wl;
                c[2] += b3 * wl;
            }
            {
                const float w2 = cw[4096 + k], w3 = cw[5120 + k];
                const float b1 = cb[3072 + k], b2 = cb[4096 + k], b3 = cb[5120 + k];
                c[3] += w2 * w3 * b1 * wl;
                c[4] += w3 * b2 * wl;
                c[5] += b3 * wl;
            }
        }
        const int lane = tid & 63, wv = tid >> 6;
#pragma unroll
        for (int j = 0; j < 6; ++j)
#pragma unroll
            for (int m = 1; m < 64; m <<= 1) c[j] += __shfl_xor(c[j], m, 64);
        if (lane == 0)
#pragma unroll
            for (int j = 0; j < 6; ++j) red[wv][j] = c[j];
        __syncthreads();
        if (tid < 6) czz[tid] = red[0][tid] + red[1][tid] + red[2][tid] + red[3][tid];
    }
}

// ---------------------------------------------------------------------------
// stage_tile (4-wave): global_load_lds dwordx4, pre-swizzled global source,
// linear LDS dest.  LDS: [row][64] bf16, 16B chunk c holds k-chunk c^(row&7).
// ---------------------------------------------------------------------------
template <int ROWS>
static __device__ __forceinline__ void stage_tile(
    const unsigned short* __restrict__ src, int K, int rowBase, int kt,
    unsigned short* lds, int w, int lane) {
    const int r8   = lane >> 3;
    const int slot = lane & 7;
#pragma unroll
    for (int q = 0; q < ROWS / 32; ++q) {
        const int blk   = q * 4 + w;
        const int row   = blk * 8 + r8;
        const int chunk = slot ^ (row & 7);
        const unsigned short* g = src + (size_t)(rowBase + row) * K + kt * 64 + chunk * 8;
        gload16(g, lds + blk * 512);
    }
}

// stage (8-wave / 512-thread variant)
template <int ROWS>
static __device__ __forceinline__ void stage8(
    const unsigned short* __restrict__ src, int K, int rowBase, int kt,
    unsigned short* lds, int w, int lane) {
    const int r8   = lane >> 3;
    const int slot = lane & 7;
#pragma unroll
    for (int q = 0; q < ROWS / 64; ++q) {
        const int blk   = q * 8 + w;
        const int row   = blk * 8 + r8;
        const int chunk = slot ^ (row & 7);
        const unsigned short* g = src + (size_t)(rowBase + row) * K + kt * 64 + chunk * 8;
        gload16(g, lds + blk * 512);
    }
}

// ---------------------------------------------------------------------------
// gemm_bf16: d1 = relu(xb @ W1b^T + b1).  Tile 128x128, BK=64, 4 waves (2x2).
// Both operands bf16 via global_load_lds (the proven-fast path).
// SINGLE barrier per K-step: stage(kt+1) at top -> compute(kt) -> vmcnt(0)
// -> barrier.  Loads span the whole iteration.
// Epilogue: LDS-bounce -> coalesced dwordx4 stores (2/thread, not 64 shorts).
// Cols 500-507 spill raw f32 accumulators to zparts (cross dots + xsum).
// ---------------------------------------------------------------------------
__global__ __launch_bounds__(256) void gemm_bf16(
    const unsigned short* __restrict__ A,    // 16384 x 1024 bf16
    const unsigned short* __restrict__ Bw,   // 512 x 1024 bf16 (N x K)
    const float* __restrict__ bias,          // b1 (500)
    unsigned short* __restrict__ C,          // 16384 x 512 bf16
    float* __restrict__ zparts) {            // B_ROWS x 8 f32
    constexpr int K = 1024, ldc = 512, BM = 128, nK = 16;
    __shared__ unsigned short As[2][BM * 64];   // 32 KB (also C-bounce buffer)
    __shared__ unsigned short Bs[2][128 * 64];  // 32 KB

    const int tid  = threadIdx.x;
    const int lane = tid & 63;
    const int wid  = tid >> 6;
    const int wm   = wid >> 1;
    const int wn   = wid & 1;
    const int g    = lane >> 4;
    const int r16  = lane & 15;

    const int cpx = gridDim.x >> 3;
    const int swz = (blockIdx.x & 7) * cpx + (blockIdx.x >> 3);
    const int rowBase = (swz >> 2) * BM;       // 4 col tiles (512/128)
    const int colBase = (swz & 3) << 7;

    f32x4 acc[4][4];
#pragma unroll
    for (int m = 0; m < 4; ++m)
#pragma unroll
        for (int n = 0; n < 4; ++n)
            acc[m][n] = (f32x4){0.f, 0.f, 0.f, 0.f};

    // ---- prologue ----
    stage_tile<BM>(A, K, rowBase, 0, As[0], wid, lane);
    stage_tile<128>(Bw, K, colBase, 0, Bs[0], wid, lane);
    asm volatile("s_waitcnt vmcnt(0)" ::: "memory");
    __builtin_amdgcn_s_barrier();
    asm volatile("" ::: "memory");

    // ---- main loop: ONE barrier per K-step ----
    for (int kt = 0; kt < nK; ++kt) {
        const int buf = kt & 1;
        if (kt + 1 < nK) {
            stage_tile<BM>(A, K, rowBase, kt + 1, As[buf ^ 1], wid, lane);
            stage_tile<128>(Bw, K, colBase, kt + 1, Bs[buf ^ 1], wid, lane);
        }
        asm volatile("" ::: "memory");

        const unsigned short* Ab = As[buf];
        const unsigned short* Bb = Bs[buf];
#pragma unroll
        for (int ks = 0; ks < 2; ++ks) {
            s16x8 af[4], bfr[4];
#pragma unroll
            for (int m = 0; m < 4; ++m) {
                const int row = wm * 64 + m * 16 + r16;
                const int off = ((ks * 4 + g) * 16) ^ ((row & 7) << 4);
                af[m] = *(const s16x8*)((const char*)Ab + row * 128 + off);
            }
#pragma unroll
            for (int n = 0; n < 4; ++n) {
                const int row = wn * 64 + n * 16 + r16;
                const int off = ((ks * 4 + g) * 16) ^ ((row & 7) << 4);
                bfr[n] = *(const s16x8*)((const char*)Bb + row * 128 + off);
            }
#pragma unroll
            for (int m = 0; m < 4; ++m)
#pragma unroll
                for (int n = 0; n < 4; ++n)
                    acc[m][n] = __builtin_amdgcn_mfma_f32_16x16x32_bf16(af[m], bfr[n], acc[m][n], 0, 0, 0);
        }

        if (kt + 1 < nK)
            asm volatile("s_waitcnt vmcnt(0)" ::: "memory");
        __builtin_amdgcn_s_barrier();
        asm volatile("" ::: "memory");
    }

    // ---- epilogue: zparts raw spill + bias/relu into LDS bounce buffer ----
    unsigned short* Cb = As[0];   // 32 KB contiguous (As[0]+As[1])
#pragma unroll
    for (int n = 0; n < 4; ++n) {
        const int col = colBase + wn * 64 + n * 16 + r16;
        const int lcol = wn * 64 + n * 16 + r16;
        const float bv = (col < 500) ? bias[col] : 0.f;
        const unsigned pc = (unsigned)(col - 500);
#pragma unroll
        for (int m = 0; m < 4; ++m) {
            const int lrow = wm * 64 + m * 16 + g * 4;
#pragma unroll
            for (int r = 0; r < 4; ++r) {
                const float raw = acc[m][n][r];
                if (pc < 8u) zparts[(size_t)(rowBase + lrow + r) * 8 + pc] = raw;
                float v = raw + bv;
                v = v > 0.f ? v : 0.f;
                Cb[(lrow + r) * 128 + lcol] = f2bf(v);
            }
        }
    }
    __syncthreads();

    // coalesced copy-out: thread t -> row t>>1, 64-col half t&1 (128B each)
    {
        const int row  = tid >> 1;
        const int half = tid & 1;
        const uint4* s = (const uint4*)(Cb + row * 128 + half * 64);
        uint4* d = (uint4*)(C + (size_t)(rowBase + row) * ldc + colBase + half * 64);
        d[0] = s[0];
        d[1] = s[1];
        d[2] = s[2];
        d[3] = s[3];
    }
}

// ---------------------------------------------------------------------------
// tail_fused (8 waves / 512 threads, 2M x 4N wave grid): per 64-row block —
//   phase 1: P = relu(d1[64x512] @ W2b^T + b2)  (64x256 bf16 in LDS)
//   phase 2: acc2 = P @ W3b^T
//   epilogue: tail = relu(acc2 + b3) . Wl[1024:]
//   final: z_i = Horner(zparts, s) + czz_i + tail + bl; out = sigmoid(z_i)
// ---------------------------------------------------------------------------
__global__ __launch_bounds__(512) void tail_fused(
    const unsigned short* __restrict__ d1,   // 16384 x 512 bf16
    const unsigned short* __restrict__ W2b,  // 256 x 512 bf16 (N x K)
    const float* __restrict__ b2,
    const unsigned short* __restrict__ W3b,  // 256 x 256 bf16 (N x K)
    const float* __restrict__ b3,
    const float* __restrict__ Wl,            // 1224 floats
    const float* __restrict__ bl,
    const float* __restrict__ zparts,        // B_ROWS x 8
    const float* __restrict__ czz,           // 6
    float* __restrict__ out) {
    __shared__ unsigned short As[2][64 * 64];
    __shared__ unsigned short Bs[2][256 * 64];
    __shared__ unsigned short P[64 * 256];
    __shared__ float part[8][64];

    const int tid  = threadIdx.x;
    const int lane = tid & 63;
    const int wid  = tid >> 6;     // 0..7
    const int wm   = wid >> 2;     // 0..1 (rows)
    const int wn   = wid & 3;      // 0..3 (cols)
    const int g    = lane >> 4;
    const int r16  = lane & 15;
    const int rowBase = blockIdx.x << 6;

    f32x4 acc[2][4];
#pragma unroll
    for (int m = 0; m < 2; ++m)
#pragma unroll
        for (int n = 0; n < 4; ++n)
            acc[m][n] = (f32x4){0.f, 0.f, 0.f, 0.f};

    // ---- phase 1: d1[64x512] @ W2b(256x512) ----
    stage8<64>(d1, 512, rowBase, 0, As[0], wid, lane);
    stage8<256>(W2b, 512, 0, 0, Bs[0], wid, lane);

    for (int kt = 0; kt < 8; ++kt) {
        const int buf = kt & 1;
        if (kt + 1 < 8) {
            stage8<64>(d1, 512, rowBase, kt + 1, As[buf ^ 1], wid, lane);
            stage8<256>(W2b, 512, 0, kt + 1, Bs[buf ^ 1], wid, lane);
            asm volatile("s_waitcnt vmcnt(5)" ::: "memory");
        } else {
            asm volatile("s_waitcnt vmcnt(0)" ::: "memory");
        }
        __builtin_amdgcn_s_barrier();
        asm volatile("" ::: "memory");

        const unsigned short* Ab = As[buf];
        const unsigned short* Bb = Bs[buf];
#pragma unroll
        for (int ks = 0; ks < 2; ++ks) {
            s16x8 af[2], bfr[4];
#pragma unroll
            for (int m = 0; m < 2; ++m) {
                const int row = wm * 32 + m * 16 + r16;
                const int off = ((ks * 4 + g) * 16) ^ ((row & 7) << 4);
                af[m] = *(const s16x8*)((const char*)Ab + row * 128 + off);
            }
#pragma unroll
            for (int n = 0; n < 4; ++n) {
                const int row = wn * 64 + n * 16 + r16;
                const int off = ((ks * 4 + g) * 16) ^ ((row & 7) << 4);
                bfr[n] = *(const s16x8*)((const char*)Bb + row * 128 + off);
            }
#pragma unroll
            for (int m = 0; m < 2; ++m)
#pragma unroll
                for (int n = 0; n < 4; ++n)
                    acc[m][n] = __builtin_amdgcn_mfma_f32_16x16x32_bf16(af[m], bfr[n], acc[m][n], 0, 0, 0);
        }
        asm volatile("s_waitcnt lgkmcnt(0)" ::: "memory");
        __builtin_amdgcn_s_barrier();
        asm volatile("" ::: "memory");
    }

    // ---- phase-1 epilogue: bias + relu + bf16 -> P (XOR-swizzled) ----
#pragma unroll
    for (int n = 0; n < 4; ++n) {
        const int col = wn * 64 + n * 16 + r16;
        const float bv = (col < 200) ? b2[col] : 0.f;
#pragma unroll
        for (int m = 0; m < 2; ++m) {
#pragma unroll
            for (int r = 0; r < 4; ++r) {
                const int row = wm * 32 + m * 16 + g * 4 + r;
                float v = acc[m][n][r] + bv;
                v = v > 0.f ? v : 0.f;
                const int byte = row * 512 + ((col * 2) ^ ((row & 7) << 4));
                *(unsigned short*)((char*)P + byte) = f2bf(v);
            }
        }
    }

    // ---- phase 2: P(64x256) @ W3b(256x256) ----
    stage8<256>(W3b, 256, 0, 0, Bs[0], wid, lane);
    asm volatile("s_waitcnt lgkmcnt(0)" ::: "memory");  // P writes done
    __builtin_amdgcn_s_barrier();
    asm volatile("" ::: "memory");

    f32x4 acc2[2][4];
#pragma unroll
    for (int m = 0; m < 2; ++m)
#pragma unroll
        for (int n = 0; n < 4; ++n)
            acc2[m][n] = (f32x4){0.f, 0.f, 0.f, 0.f};

    for (int kt = 0; kt < 4; ++kt) {
        const int buf = kt & 1;
        if (kt + 1 < 4) {
            stage8<256>(W3b, 256, 0, kt + 1, Bs[buf ^ 1], wid, lane);
            asm volatile("s_waitcnt vmcnt(4)" ::: "memory");
        } else {
            asm volatile("s_waitcnt vmcnt(0)" ::: "memory");
        }
        __builtin_amdgcn_s_barrier();
        asm volatile("" ::: "memory");

        const unsigned short* Bb = Bs[buf];
#pragma unroll
        for (int ks = 0; ks < 2; ++ks) {
            s16x8 af[2], bfr[4];
#pragma unroll
            for (int m = 0; m < 2; ++m) {
                const int row = wm * 32 + m * 16 + r16;
                const int byte = row * 512 + ((kt * 128 + (ks * 4 + g) * 16) ^ ((row & 7) << 4));
                af[m] = *(const s16x8*)((const char*)P + byte);
            }
#pragma unroll
            for (int n = 0; n < 4; ++n) {
                const int row = wn * 64 + n * 16 + r16;
                const int off = ((ks * 4 + g) * 16) ^ ((row & 7) << 4);
                bfr[n] = *(const s16x8*)((const char*)Bb + row * 128 + off);
            }
#pragma unroll
            for (int m = 0; m < 2; ++m)
#pragma unroll
                for (int n = 0; n < 4; ++n)
                    acc2[m][n] = __builtin_amdgcn_mfma_f32_16x16x32_bf16(af[m], bfr[n], acc2[m][n], 0, 0, 0);
        }
        asm volatile("s_waitcnt lgkmcnt(0)" ::: "memory");
        __builtin_amdgcn_s_barrier();
        asm volatile("" ::: "memory");
    }

    // ---- tail dot ----
    float wlv[4], b3v[4];
#pragma unroll
    for (int n = 0; n < 4; ++n) {
        const int col = wn * 64 + n * 16 + r16;
        wlv[n] = (col < 200) ? Wl[1024 + col] : 0.f;
        b3v[n] = (col < 200) ? b3[col] : 0.f;
    }
#pragma unroll
    for (int m = 0; m < 2; ++m) {
#pragma unroll
        for (int r = 0; r < 4; ++r) {
            float s = 0.f;
#pragma unroll
            for (int n = 0; n < 4; ++n) {
                float v = acc2[m][n][r] + b3v[n];
                v = v > 0.f ? v : 0.f;
                s += v * wlv[n];
            }
            s += __shfl_xor(s, 1, 64);
            s += __shfl_xor(s, 2, 64);
            s += __shfl_xor(s, 4, 64);
            s += __shfl_xor(s, 8, 64);
            if (r16 == 0) part[wid][wm * 32 + m * 16 + g * 4 + r] = s;
        }
    }
    __syncthreads();

    // ---- final: cross-net Horner combine + sigmoid ----
    if (tid < 64) {
        const int row = rowBase + tid;
        const int wmr = (tid >> 5) << 2;
        const float t = part[wmr][tid] + part[wmr + 1][tid] +
                        part[wmr + 2][tid] + part[wmr + 3][tid];
        const float blv = bl[0];
        const float* zp = zparts + (size_t)row * 8;
        float4 zpa = *(const float4*)(zp);       // P3_0 P2_0 P1_0 P3_1
        float4 zpb = *(const float4*)(zp + 4);   // P2_1 P1_1 P0   s
        const float s = zpb.w;
        const float z0 = ((zpa.x * s + zpa.y + czz[0]) * s + zpa.z + czz[1]) * s
                         + zpb.z + czz[2] + t + blv;
        const float z1 = ((zpa.w * s + zpb.x + czz[3]) * s + zpb.y + czz[4]) * s
                         + zpb.z + czz[5] + t + blv;
        out[row]          = 1.f / (1.f + expf(-z0));
        out[B_ROWS + row] = 1.f / (1.f + expf(-z1));
    }
}

// ---------------------------------------------------------------------------
extern "C" void kernel_launch(void* const* d_in, const int* in_sizes, int n_in,
                              void* d_out, int out_size, void* d_ws, size_t ws_size,
                              hipStream_t stream) {
    const float* x  = (const float*)d_in[0];
    const float* W1 = (const float*)d_in[3];
    const float* b1 = (const float*)d_in[4];
    const float* W2 = (const float*)d_in[5];
    const float* b2 = (const float*)d_in[6];
    const float* W3 = (const float*)d_in[7];
    const float* b3 = (const float*)d_in[8];
    const float* Wl = (const float*)d_in[9];
    const float* bl = (const float*)d_in[10];
    const float* cw = (const float*)d_in[11];
    const float* cb = (const float*)d_in[12];
    float* out = (float*)d_out;

    unsigned short* xb  = (unsigned short*)d_ws;          // 16384 x 1024
    unsigned short* d1  = xb + (size_t)16384 * 1024;      // 16384 x 512
    unsigned short* W1b = d1 + (size_t)16384 * 512;       // 512 x 1024
    unsigned short* W2b = W1b + (size_t)512 * 1024;       // 256 x 512
    unsigned short* W3b = W2b + (size_t)256 * 512;        // 256 x 256
    float* zparts = (float*)(W3b + (size_t)256 * 256);    // 16384 x 8
    float* czz = zparts + (size_t)16384 * 8;              // 6

    // x convert + weight transpose + cross-net P-vectors/constants
    prep<<<4274, 256, 0, stream>>>(x, xb, W1, W2, W3, cw, cb, Wl,
                                   W1b, W2b, W3b, czz);

    // d1 = relu(xb @ W1 + b1); cols 500-507 spill raw cross dots to zparts
    gemm_bf16<<<512, 256, 0, stream>>>(xb, W1b, b1, d1, zparts);

    // d2/d3/tail/cross-combine/sigmoid fused
    tail_fused<<<256, 512, 0, stream>>>(d1, W2b, b2, W3b, b3, Wl, bl,
                                        zparts, czz, out);
}

// Round 11
// 55.310 us; speedup vs baseline: 1.1111x; 1.1111x over previous
//
#include <hip/hip_runtime.h>
#include <hip/hip_bf16.h>
#include <math.h>

#define B_ROWS 16384
#define DIM 1024

typedef __attribute__((ext_vector_type(8))) short s16x8;
typedef __attribute__((ext_vector_type(4))) float f32x4;

static __device__ __forceinline__ unsigned short f2bf(float f) {
    union { float f; unsigned u; } v; v.f = f;
    unsigned r = v.u + 0x7FFF + ((v.u >> 16) & 1);  // RNE
    return (unsigned short)(r >> 16);
}

// packed f32x2 -> bf16x2 (RNE), single HW instruction
static __device__ __forceinline__ unsigned cvt_pk_bf16(float lo, float hi) {
    unsigned r;
    asm volatile("v_cvt_pk_bf16_f32 %0, %1, %2" : "=v"(r) : "v"(lo), "v"(hi));
    return r;
}

// async global -> LDS, 16 bytes per lane; lds base wave-uniform, HW adds lane*16
static __device__ __forceinline__ void gload16(const unsigned short* g, unsigned short* l) {
    __builtin_amdgcn_global_load_lds(
        (const __attribute__((address_space(1))) unsigned int*)g,
        (__attribute__((address_space(3))) unsigned int*)l, 16, 0, 0);
}

// ---------------------------------------------------------------------------
// prep (178 blocks): weight transpose+convert+pad (64x64 LDS tiles) +
// cross-net P-vector rows into W1b spare rows + scalar constants czz[6].
// Cross-net closed form (exact algebra):
//   z_i = s^3(x.P3_i)+s^2(x.P2_i)+s(x.P1_i)+(x.Wl)+s^2 C2_i+s C1_i+C0_i
// W1b rows: 500:P3_0 501:P2_0 502:P1_0 503:P3_1 504:P2_1 505:P1_1 506:Wl
//           507:ones (row-sum s)  508-511: zero
// ---------------------------------------------------------------------------
__global__ __launch_bounds__(256) void prep(
    const float* __restrict__ W1, const float* __restrict__ W2,
    const float* __restrict__ W3,
    const float* __restrict__ cw, const float* __restrict__ cb,
    const float* __restrict__ Wl,
    unsigned short* __restrict__ W1b, unsigned short* __restrict__ W2b,
    unsigned short* __restrict__ W3b,
    float* __restrict__ czz) {
    __shared__ unsigned short tile[64][72];
    __shared__ float red[4][6];
    const int tid = threadIdx.x;
    const int blk = blockIdx.x;

    if (blk < 176) {
        const int w = blk;
        const float* src; unsigned short* dst;
        int kt, nt, Ksrc, Nsrc, ldDst;
        bool skipHi = false;
        if (w < 128)      { kt = w & 15;         nt = w >> 4;         src = W1; dst = W1b; Ksrc = 1024; Nsrc = 500; ldDst = 1024; skipHi = true; }
        else if (w < 160) { kt = (w - 128) & 7;  nt = (w - 128) >> 3; src = W2; dst = W2b; Ksrc = 500;  Nsrc = 200; ldDst = 512;  }
        else              { kt = (w - 160) & 3;  nt = (w - 160) >> 2; src = W3; dst = W3b; Ksrc = 200;  Nsrc = 200; ldDst = 256;  }
        const int k0 = kt << 6, n0 = nt << 6;
        {
            const int r = tid >> 2, c0 = (tid & 3) << 4;
            const int kk = k0 + r;
#pragma unroll
            for (int i = 0; i < 16; ++i) {
                const int nn = n0 + c0 + i;
                const float v = (kk < Ksrc && nn < Nsrc) ? src[(size_t)kk * Nsrc + nn] : 0.f;
                tile[r][c0 + i] = f2bf(v);
            }
        }
        __syncthreads();
        {
            const int n = tid >> 2, kc = (tid & 3) << 4;
            if (!(skipHi && (n0 + n) >= 500)) {   // rows 500-511 owned by blk 176
                unsigned short* o = dst + (size_t)(n0 + n) * ldDst + k0 + kc;
#pragma unroll
                for (int i = 0; i < 16; ++i) o[i] = tile[kc + i][n];
            }
        }
    } else if (blk == 176) {
        // ---- P-vector rows ----
#pragma unroll
        for (int q = 0; q < 4; ++q) {
            const int k = tid * 4 + q;
            const float wl = Wl[k];
            const float a1 = cw[k],         a2 = cw[1024 + k],  a3 = cw[2048 + k];
            const float d1_ = cw[3072 + k], d2_ = cw[4096 + k], d3_ = cw[5120 + k];
            W1b[(size_t)500 * 1024 + k] = f2bf(a1 * a2 * a3 * wl);
            W1b[(size_t)501 * 1024 + k] = f2bf(a2 * a3 * wl);
            W1b[(size_t)502 * 1024 + k] = f2bf(a3 * wl);
            W1b[(size_t)503 * 1024 + k] = f2bf(d1_ * d2_ * d3_ * wl);
            W1b[(size_t)504 * 1024 + k] = f2bf(d2_ * d3_ * wl);
            W1b[(size_t)505 * 1024 + k] = f2bf(d3_ * wl);
            W1b[(size_t)506 * 1024 + k] = f2bf(wl);
            W1b[(size_t)507 * 1024 + k] = 0x3F80;   // bf16 1.0
            W1b[(size_t)508 * 1024 + k] = 0;
            W1b[(size_t)509 * 1024 + k] = 0;
            W1b[(size_t)510 * 1024 + k] = 0;
            W1b[(size_t)511 * 1024 + k] = 0;
        }
    } else {
        // ---- C scalars (f32 exact) ----
        float c[6] = {0.f, 0.f, 0.f, 0.f, 0.f, 0.f};
#pragma unroll
        for (int q = 0; q < 4; ++q) {
            const int k = tid * 4 + q;
            const float wl = Wl[k];
            {
                const float w2 = cw[1024 + k], w3 = cw[2048 + k];
                const float b1 = cb[k], b2 = cb[1024 + k], b3 = cb[2048 + k];
                c[0] += w2 * w3 * b1 * wl;
                c[1] += w3 * b2 * wl;
                c[2] += b3 * wl;
            }
            {
                const float w2 = cw[4096 + k], w3 = cw[5120 + k];
                const float b1 = cb[3072 + k], b2 = cb[4096 + k], b3 = cb[5120 + k];
                c[3] += w2 * w3 * b1 * wl;
                c[4] += w3 * b2 * wl;
                c[5] += b3 * wl;
            }
        }
        const int lane = tid & 63, wv = tid >> 6;
#pragma unroll
        for (int j = 0; j < 6; ++j)
#pragma unroll
            for (int m = 1; m < 64; m <<= 1) c[j] += __shfl_xor(c[j], m, 64);
        if (lane == 0)
#pragma unroll
            for (int j = 0; j < 6; ++j) red[wv][j] = c[j];
        __syncthreads();
        if (tid < 6) czz[tid] = red[0][tid] + red[1][tid] + red[2][tid] + red[3][tid];
    }
}

// ---------------------------------------------------------------------------
// stage8 (8-wave / 512-thread): global_load_lds dwordx4, pre-swizzled global
// source, linear LDS dest.  LDS: [row][64] bf16, 16B chunk c = k-chunk c^(row&7).
// ---------------------------------------------------------------------------
template <int ROWS>
static __device__ __forceinline__ void stage8(
    const unsigned short* __restrict__ src, int K, int rowBase, int kt,
    unsigned short* lds, int w, int lane) {
    const int r8   = lane >> 3;
    const int slot = lane & 7;
#pragma unroll
    for (int q = 0; q < ROWS / 64; ++q) {
        const int blk   = q * 8 + w;
        const int row   = blk * 8 + r8;
        const int chunk = slot ^ (row & 7);
        const unsigned short* g = src + (size_t)(rowBase + row) * K + kt * 64 + chunk * 8;
        gload16(g, lds + blk * 512);
    }
}

// ---------------------------------------------------------------------------
// gemm_xa: d1 = relu(x @ W1 + b1) reading x as f32 DIRECTLY (no convert pass).
// Tile 128x128, BK=64, 8 waves (2M x 4N; each wave 64x32, acc[4][2]).
// 512 threads halve per-wave staging/compute; LDS 64 KB -> 2 blocks/CU ->
// 16 waves/CU = 4 waves/SIMD (the R9 version had only 2).
// A: reg-staged f32 (4 float4/thread, coalesced 64B/lane) -> cvt_pk ->
//    swizzled ds_write; issue A BEFORE B so cvt's implicit wait is vmcnt(2).
// B: global_load_lds.  One vmcnt(0)+lgkmcnt(0)+barrier per K-step.
// Epilogue: LDS-bounce -> coalesced dwordx4 stores.
// Cols 500-507 spill raw f32 accumulators to zparts (cross dots + xsum).
// ---------------------------------------------------------------------------
__global__ __launch_bounds__(512, 4) void gemm_xa(
    const float* __restrict__ X,             // 16384 x 1024 f32
    const unsigned short* __restrict__ Bw,   // 512 x 1024 bf16 (N x K)
    const float* __restrict__ bias,          // b1 (500)
    unsigned short* __restrict__ C,          // 16384 x 512 bf16
    float* __restrict__ zparts) {            // B_ROWS x 8 f32
    constexpr int K = 1024, ldc = 512, nK = 16;
    __shared__ unsigned short As[2][128 * 64];   // 32 KB (reused as C bounce)
    __shared__ unsigned short Bs[2][128 * 64];   // 32 KB

    const int tid  = threadIdx.x;
    const int lane = tid & 63;
    const int wid  = tid >> 6;     // 0..7
    const int wm   = wid >> 2;     // 0..1 (64-row halves)
    const int wn   = wid & 3;      // 0..3 (32-col quarters)
    const int g    = lane >> 4;
    const int r16  = lane & 15;

    const int cpx = gridDim.x >> 3;
    const int swz = (blockIdx.x & 7) * cpx + (blockIdx.x >> 3);
    const int rowBase = (swz >> 2) << 7;       // 4 col tiles (512/128)
    const int colBase = (swz & 3) << 7;

    // A staging: thread t covers row t>>2, f32 k-slice (t&3)*16 (64B, coalesced)
    const int arow = tid >> 2;                 // 0..127
    const int ak   = (tid & 3) << 4;           // f32 offset within BK=64
    const float* aSrc = X + (size_t)(rowBase + arow) * K + ak;

    float4 a_regs[4];

    f32x4 acc[4][2];
#pragma unroll
    for (int m = 0; m < 4; ++m)
#pragma unroll
        for (int n = 0; n < 2; ++n)
            acc[m][n] = (f32x4){0.f, 0.f, 0.f, 0.f};

    auto issue_A = [&](int kt) {
#pragma unroll
        for (int q = 0; q < 4; ++q)
            a_regs[q] = *(const float4*)(aSrc + kt * 64 + q * 4);
    };
    // 16 f32 -> 32B bf16 = 2 swizzled 16B chunks at (t&3)*2 + {0,1}
    auto cvt_write_A = [&](unsigned short* dst) {
        const int cb = (tid & 3) << 1;
        uint4 v0, v1;
        v0.x = cvt_pk_bf16(a_regs[0].x, a_regs[0].y);
        v0.y = cvt_pk_bf16(a_regs[0].z, a_regs[0].w);
        v0.z = cvt_pk_bf16(a_regs[1].x, a_regs[1].y);
        v0.w = cvt_pk_bf16(a_regs[1].z, a_regs[1].w);
        v1.x = cvt_pk_bf16(a_regs[2].x, a_regs[2].y);
        v1.y = cvt_pk_bf16(a_regs[2].z, a_regs[2].w);
        v1.z = cvt_pk_bf16(a_regs[3].x, a_regs[3].y);
        v1.w = cvt_pk_bf16(a_regs[3].z, a_regs[3].w);
        const int ch0 = (cb + 0) ^ (arow & 7);
        const int ch1 = (cb + 1) ^ (arow & 7);
        *(uint4*)((char*)dst + arow * 128 + ch0 * 16) = v0;
        *(uint4*)((char*)dst + arow * 128 + ch1 * 16) = v1;
    };

    // ---- prologue: tile 0 ----
    issue_A(0);
    asm volatile("" ::: "memory");
    stage8<128>(Bw, K, colBase, 0, Bs[0], wid, lane);
    asm volatile("" ::: "memory");
    cvt_write_A(As[0]);                        // implicit vmcnt(2) on a_regs
    asm volatile("s_waitcnt vmcnt(0)" ::: "memory");
    asm volatile("s_waitcnt lgkmcnt(0)" ::: "memory");
    __builtin_amdgcn_s_barrier();
    asm volatile("" ::: "memory");

    // ---- main loop: one barrier per K-step ----
    for (int kt = 0; kt < nK; ++kt) {
        const int buf = kt & 1;
        if (kt + 1 < nK) {
            issue_A(kt + 1);                   // oldest in queue
            asm volatile("" ::: "memory");
            stage8<128>(Bw, K, colBase, kt + 1, Bs[buf ^ 1], wid, lane);
            asm volatile("" ::: "memory");
        }

        // compute(kt): 16 MFMA/wave
        const unsigned short* Ab = As[buf];
        const unsigned short* Bb = Bs[buf];
#pragma unroll
        for (int ks = 0; ks < 2; ++ks) {
            s16x8 af[4], bfr[2];
#pragma unroll
            for (int m = 0; m < 4; ++m) {
                const int row = wm * 64 + m * 16 + r16;
                const int off = ((ks * 4 + g) * 16) ^ ((row & 7) << 4);
                af[m] = *(const s16x8*)((const char*)Ab + row * 128 + off);
            }
#pragma unroll
            for (int n = 0; n < 2; ++n) {
                const int row = wn * 32 + n * 16 + r16;
                const int off = ((ks * 4 + g) * 16) ^ ((row & 7) << 4);
                bfr[n] = *(const s16x8*)((const char*)Bb + row * 128 + off);
            }
#pragma unroll
            for (int m = 0; m < 4; ++m)
#pragma unroll
                for (int n = 0; n < 2; ++n)
                    acc[m][n] = __builtin_amdgcn_mfma_f32_16x16x32_bf16(af[m], bfr[n], acc[m][n], 0, 0, 0);
        }

        if (kt + 1 < nK) {
            cvt_write_A(As[buf ^ 1]);          // a_regs aged by full compute
        }
        asm volatile("s_waitcnt vmcnt(0)" ::: "memory");   // B(kt+1) landed
        asm volatile("s_waitcnt lgkmcnt(0)" ::: "memory"); // ds_writes done
        __builtin_amdgcn_s_barrier();
        asm volatile("" ::: "memory");
    }

    // ---- epilogue: zparts raw spill + bias/relu into LDS bounce ----
    unsigned short* Cb = As[0];   // 32 KB contiguous = full 128x128 bf16 tile
#pragma unroll
    for (int n = 0; n < 2; ++n) {
        const int lcol = wn * 32 + n * 16 + r16;
        const int col = colBase + lcol;
        const float bv = (col < 500) ? bias[col] : 0.f;
        const unsigned pc = (unsigned)(col - 500);
#pragma unroll
        for (int m = 0; m < 4; ++m) {
            const int lrow = wm * 64 + m * 16 + g * 4;
#pragma unroll
            for (int r = 0; r < 4; ++r) {
                const float raw = acc[m][n][r];
                if (pc < 8u) zparts[(size_t)(rowBase + lrow + r) * 8 + pc] = raw;
                float v = raw + bv;
                v = v > 0.f ? v : 0.f;
                Cb[(lrow + r) * 128 + lcol] = f2bf(v);
            }
        }
    }
    __syncthreads();

    // coalesced copy-out: thread t -> row t>>2, 32-col quarter t&3 (64B)
    {
        const int row = tid >> 2;
        const int q   = tid & 3;
        const uint4* s = (const uint4*)(Cb + row * 128 + q * 32);
        uint4* d = (uint4*)(C + (size_t)(rowBase + row) * ldc + colBase + q * 32);
        d[0] = s[0];
        d[1] = s[1];
    }
}

// ---------------------------------------------------------------------------
// tail_fused (8 waves / 512 threads, 2M x 4N wave grid): per 64-row block —
//   phase 1: P = relu(d1[64x512] @ W2b^T + b2)  (64x256 bf16 in LDS)
//   phase 2: acc2 = P @ W3b^T
//   epilogue: tail = relu(acc2 + b3) . Wl[1024:]
//   final: z_i = Horner(zparts, s) + czz_i + tail + bl; out = sigmoid(z_i)
// ---------------------------------------------------------------------------
__global__ __launch_bounds__(512) void tail_fused(
    const unsigned short* __restrict__ d1,   // 16384 x 512 bf16
    const unsigned short* __restrict__ W2b,  // 256 x 512 bf16 (N x K)
    const float* __restrict__ b2,
    const unsigned short* __restrict__ W3b,  // 256 x 256 bf16 (N x K)
    const float* __restrict__ b3,
    const float* __restrict__ Wl,            // 1224 floats
    const float* __restrict__ bl,
    const float* __restrict__ zparts,        // B_ROWS x 8
    const float* __restrict__ czz,           // 6
    float* __restrict__ out) {
    __shared__ unsigned short As[2][64 * 64];
    __shared__ unsigned short Bs[2][256 * 64];
    __shared__ unsigned short P[64 * 256];
    __shared__ float part[8][64];

    const int tid  = threadIdx.x;
    const int lane = tid & 63;
    const int wid  = tid >> 6;     // 0..7
    const int wm   = wid >> 2;     // 0..1 (rows)
    const int wn   = wid & 3;      // 0..3 (cols)
    const int g    = lane >> 4;
    const int r16  = lane & 15;
    const int rowBase = blockIdx.x << 6;

    f32x4 acc[2][4];
#pragma unroll
    for (int m = 0; m < 2; ++m)
#pragma unroll
        for (int n = 0; n < 4; ++n)
            acc[m][n] = (f32x4){0.f, 0.f, 0.f, 0.f};

    // ---- phase 1: d1[64x512] @ W2b(256x512) ----
    stage8<64>(d1, 512, rowBase, 0, As[0], wid, lane);
    stage8<256>(W2b, 512, 0, 0, Bs[0], wid, lane);

    for (int kt = 0; kt < 8; ++kt) {
        const int buf = kt & 1;
        if (kt + 1 < 8) {
            stage8<64>(d1, 512, rowBase, kt + 1, As[buf ^ 1], wid, lane);
            stage8<256>(W2b, 512, 0, kt + 1, Bs[buf ^ 1], wid, lane);
            asm volatile("s_waitcnt vmcnt(5)" ::: "memory");
        } else {
            asm volatile("s_waitcnt vmcnt(0)" ::: "memory");
        }
        __builtin_amdgcn_s_barrier();
        asm volatile("" ::: "memory");

        const unsigned short* Ab = As[buf];
        const unsigned short* Bb = Bs[buf];
#pragma unroll
        for (int ks = 0; ks < 2; ++ks) {
            s16x8 af[2], bfr[4];
#pragma unroll
            for (int m = 0; m < 2; ++m) {
                const int row = wm * 32 + m * 16 + r16;
                const int off = ((ks * 4 + g) * 16) ^ ((row & 7) << 4);
                af[m] = *(const s16x8*)((const char*)Ab + row * 128 + off);
            }
#pragma unroll
            for (int n = 0; n < 4; ++n) {
                const int row = wn * 64 + n * 16 + r16;
                const int off = ((ks * 4 + g) * 16) ^ ((row & 7) << 4);
                bfr[n] = *(const s16x8*)((const char*)Bb + row * 128 + off);
            }
#pragma unroll
            for (int m = 0; m < 2; ++m)
#pragma unroll
                for (int n = 0; n < 4; ++n)
                    acc[m][n] = __builtin_amdgcn_mfma_f32_16x16x32_bf16(af[m], bfr[n], acc[m][n], 0, 0, 0);
        }
        asm volatile("s_waitcnt lgkmcnt(0)" ::: "memory");
        __builtin_amdgcn_s_barrier();
        asm volatile("" ::: "memory");
    }

    // ---- phase-1 epilogue: bias + relu + bf16 -> P (XOR-swizzled) ----
#pragma unroll
    for (int n = 0; n < 4; ++n) {
        const int col = wn * 64 + n * 16 + r16;
        const float bv = (col < 200) ? b2[col] : 0.f;
#pragma unroll
        for (int m = 0; m < 2; ++m) {
#pragma unroll
            for (int r = 0; r < 4; ++r) {
                const int row = wm * 32 + m * 16 + g * 4 + r;
                float v = acc[m][n][r] + bv;
                v = v > 0.f ? v : 0.f;
                const int byte = row * 512 + ((col * 2) ^ ((row & 7) << 4));
                *(unsigned short*)((char*)P + byte) = f2bf(v);
            }
        }
    }

    // ---- phase 2: P(64x256) @ W3b(256x256) ----
    stage8<256>(W3b, 256, 0, 0, Bs[0], wid, lane);
    asm volatile("s_waitcnt lgkmcnt(0)" ::: "memory");  // P writes done
    __builtin_amdgcn_s_barrier();
    asm volatile("" ::: "memory");

    f32x4 acc2[2][4];
#pragma unroll
    for (int m = 0; m < 2; ++m)
#pragma unroll
        for (int n = 0; n < 4; ++n)
            acc2[m][n] = (f32x4){0.f, 0.f, 0.f, 0.f};

    for (int kt = 0; kt < 4; ++kt) {
        const int buf = kt & 1;
        if (kt + 1 < 4) {
            stage8<256>(W3b, 256, 0, kt + 1, Bs[buf ^ 1], wid, lane);
            asm volatile("s_waitcnt vmcnt(4)" ::: "memory");
        } else {
            asm volatile("s_waitcnt vmcnt(0)" ::: "memory");
        }
        __builtin_amdgcn_s_barrier();
        asm volatile("" ::: "memory");

        const unsigned short* Bb = Bs[buf];
#pragma unroll
        for (int ks = 0; ks < 2; ++ks) {
            s16x8 af[2], bfr[4];
#pragma unroll
            for (int m = 0; m < 2; ++m) {
                const int row = wm * 32 + m * 16 + r16;
                const int byte = row * 512 + ((kt * 128 + (ks * 4 + g) * 16) ^ ((row & 7) << 4));
                af[m] = *(const s16x8*)((const char*)P + byte);
            }
#pragma unroll
            for (int n = 0; n < 4; ++n) {
                const int row = wn * 64 + n * 16 + r16;
                const int off = ((ks * 4 + g) * 16) ^ ((row & 7) << 4);
                bfr[n] = *(const s16x8*)((const char*)Bb + row * 128 + off);
            }
#pragma unroll
            for (int m = 0; m < 2; ++m)
#pragma unroll
                for (int n = 0; n < 4; ++n)
                    acc2[m][n] = __builtin_amdgcn_mfma_f32_16x16x32_bf16(af[m], bfr[n], acc2[m][n], 0, 0, 0);
        }
        asm volatile("s_waitcnt lgkmcnt(0)" ::: "memory");
        __builtin_amdgcn_s_barrier();
        asm volatile("" ::: "memory");
    }

    // ---- tail dot ----
    float wlv[4], b3v[4];
#pragma unroll
    for (int n = 0; n < 4; ++n) {
        const int col = wn * 64 + n * 16 + r16;
        wlv[n] = (col < 200) ? Wl[1024 + col] : 0.f;
        b3v[n] = (col < 200) ? b3[col] : 0.f;
    }
#pragma unroll
    for (int m = 0; m < 2; ++m) {
#pragma unroll
        for (int r = 0; r < 4; ++r) {
            float s = 0.f;
#pragma unroll
            for (int n = 0; n < 4; ++n) {
                float v = acc2[m][n][r] + b3v[n];
                v = v > 0.f ? v : 0.f;
                s += v * wlv[n];
            }
            s += __shfl_xor(s, 1, 64);
            s += __shfl_xor(s, 2, 64);
            s += __shfl_xor(s, 4, 64);
            s += __shfl_xor(s, 8, 64);
            if (r16 == 0) part[wid][wm * 32 + m * 16 + g * 4 + r] = s;
        }
    }
    __syncthreads();

    // ---- final: cross-net Horner combine + sigmoid ----
    if (tid < 64) {
        const int row = rowBase + tid;
        const int wmr = (tid >> 5) << 2;
        const float t = part[wmr][tid] + part[wmr + 1][tid] +
                        part[wmr + 2][tid] + part[wmr + 3][tid];
        const float blv = bl[0];
        const float* zp = zparts + (size_t)row * 8;
        float4 zpa = *(const float4*)(zp);       // P3_0 P2_0 P1_0 P3_1
        float4 zpb = *(const float4*)(zp + 4);   // P2_1 P1_1 P0   s
        const float s = zpb.w;
        const float z0 = ((zpa.x * s + zpa.y + czz[0]) * s + zpa.z + czz[1]) * s
                         + zpb.z + czz[2] + t + blv;
        const float z1 = ((zpa.w * s + zpb.x + czz[3]) * s + zpb.y + czz[4]) * s
                         + zpb.z + czz[5] + t + blv;
        out[row]          = 1.f / (1.f + expf(-z0));
        out[B_ROWS + row] = 1.f / (1.f + expf(-z1));
    }
}

// ---------------------------------------------------------------------------
extern "C" void kernel_launch(void* const* d_in, const int* in_sizes, int n_in,
                              void* d_out, int out_size, void* d_ws, size_t ws_size,
                              hipStream_t stream) {
    const float* x  = (const float*)d_in[0];
    const float* W1 = (const float*)d_in[3];
    const float* b1 = (const float*)d_in[4];
    const float* W2 = (const float*)d_in[5];
    const float* b2 = (const float*)d_in[6];
    const float* W3 = (const float*)d_in[7];
    const float* b3 = (const float*)d_in[8];
    const float* Wl = (const float*)d_in[9];
    const float* bl = (const float*)d_in[10];
    const float* cw = (const float*)d_in[11];
    const float* cb = (const float*)d_in[12];
    float* out = (float*)d_out;

    unsigned short* d1  = (unsigned short*)d_ws;          // 16384 x 512
    unsigned short* W1b = d1 + (size_t)16384 * 512;       // 512 x 1024
    unsigned short* W2b = W1b + (size_t)512 * 1024;       // 256 x 512
    unsigned short* W3b = W2b + (size_t)256 * 512;        // 256 x 256
    float* zparts = (float*)(W3b + (size_t)256 * 256);    // 16384 x 8
    float* czz = zparts + (size_t)16384 * 8;              // 6

    // weight transpose + cross-net P-vectors/constants
    prep<<<178, 256, 0, stream>>>(W1, W2, W3, cw, cb, Wl, W1b, W2b, W3b, czz);

    // d1 = relu(x @ W1 + b1), x read as f32 directly; cross dots -> zparts
    gemm_xa<<<512, 512, 0, stream>>>(x, W1b, b1, d1, zparts);

    // d2/d3/tail/cross-combine/sigmoid fused
    tail_fused<<<256, 512, 0, stream>>>(d1, W2b, b2, W3b, b3, Wl, bl,
                                        zparts, czz, out);
}